// Round 1
// baseline (187.158 us; speedup 1.0000x reference)
//
#include <hip/hip_runtime.h>

typedef unsigned int u32;
typedef unsigned short u16;
typedef short s16x8 __attribute__((ext_vector_type(8)));
typedef u16 u16x8 __attribute__((ext_vector_type(8)));
typedef float f32x4 __attribute__((ext_vector_type(4)));
typedef __attribute__((address_space(3))) u32 as3_u32;
typedef __attribute__((address_space(1))) const u32 as1_u32;

constexpr int MM = 16384, NN = 3072, KK = 1024;
constexpr int BM = 128, BN = 128, BK = 64;

// fp32 -> bf16 round-to-nearest-even (no NaN handling needed for this data)
__device__ __forceinline__ u16 f2bf(float f) {
  u32 u = __builtin_bit_cast(u32, f);
  u = (u + 0x7FFFu + ((u >> 16) & 1u)) >> 16;
  return (u16)u;
}

__device__ __forceinline__ void gload_lds16(const void* g, void* l) {
  __builtin_amdgcn_global_load_lds((as1_u32*)g, (as3_u32*)l, 16, 0, 0);
}

// W_eff[o][d] = w_qkv[o][d] + SCALING * (b@a)[o][d] for q (o<1024) and v (o>=2048) slices
__global__ __launch_bounds__(256) void build_weff(
    const float* __restrict__ w, const float* __restrict__ aq,
    const float* __restrict__ bq, const float* __restrict__ av,
    const float* __restrict__ bv, u16* __restrict__ weff) {
  int idx = blockIdx.x * 256 + threadIdx.x;      // 0 .. 3145727
  int o = idx >> 10, d = idx & 1023;
  float val = w[idx];
  if (o < 1024) {
    float s = 0.f;
#pragma unroll
    for (int r = 0; r < 16; ++r) s += bq[o * 16 + r] * aq[r * 1024 + d];
    val += s * 0.0625f;                          // SCALING = 1/16
  } else if (o >= 2048) {
    int o2 = o - 2048;
    float s = 0.f;
#pragma unroll
    for (int r = 0; r < 16; ++r) s += bv[o2 * 16 + r] * av[r * 1024 + d];
    val += s * 0.0625f;
  }
  weff[idx] = f2bf(val);
}

// x fp32 -> bf16, 8 elems/thread
__global__ __launch_bounds__(256) void cvt_x(const float* __restrict__ x,
                                             u16* __restrict__ xb) {
  size_t i = ((size_t)blockIdx.x * 256 + threadIdx.x) * 8;
  float4 f0 = *(const float4*)(x + i);
  float4 f1 = *(const float4*)(x + i + 4);
  u16x8 o;
  o[0] = f2bf(f0.x); o[1] = f2bf(f0.y); o[2] = f2bf(f0.z); o[3] = f2bf(f0.w);
  o[4] = f2bf(f1.x); o[5] = f2bf(f1.y); o[6] = f2bf(f1.z); o[7] = f2bf(f1.w);
  *(u16x8*)(xb + i) = o;
}

// C[m][n] = sum_k A[m][k]*B[n][k] + bias[n]
// A: bf16 [MM][KK] (or fp32 reg-staged if REGA), B: bf16 W_eff [NN][KK]
template <bool REGA>
__global__ __launch_bounds__(256) void gemm_qkv(
    const u16* __restrict__ Ab, const float* __restrict__ Af,
    const u16* __restrict__ Bw, const float* __restrict__ bias,
    float* __restrict__ C) {
  __shared__ u16 As[BM * BK];   // 16 KB
  __shared__ u16 Bs[BN * BK];   // 16 KB
  const int tid = threadIdx.x;
  const int wave = tid >> 6, lane = tid & 63;
  const int l15 = lane & 15, lk = lane >> 4;
  const int mTile = blockIdx.y * BM, nTile = blockIdx.x * BN;
  const int wr = wave >> 1, wc = wave & 1;   // 2x2 waves, 64x64 each

  f32x4 acc[4][4] = {};

  for (int k0 = 0; k0 < KK; k0 += BK) {
    // ---- stage B tile: 16 chunks of 1KB, wave w owns chunks w*4..w*4+3
#pragma unroll
    for (int j = 0; j < 4; ++j) {
      const int c = wave * 4 + j;
      const int e = c * 512 + lane * 8;        // elem idx in Bs (linear)
      const int row = e >> 6, col = e & 63;
      gload_lds16(Bw + (size_t)(nTile + row) * KK + k0 + col, Bs + c * 512);
    }
    // ---- stage A tile
    if constexpr (!REGA) {
#pragma unroll
      for (int j = 0; j < 4; ++j) {
        const int c = wave * 4 + j;
        const int e = c * 512 + lane * 8;
        const int row = e >> 6, col = e & 63;
        gload_lds16(Ab + (size_t)(mTile + row) * KK + k0 + col, As + c * 512);
      }
    } else {
#pragma unroll
      for (int j = 0; j < 4; ++j) {
        const int e = (j * 256 + tid) * 8;
        const int row = e >> 6, col = e & 63;
        const float* g = Af + (size_t)(mTile + row) * KK + k0 + col;
        float4 f0 = *(const float4*)g;
        float4 f1 = *(const float4*)(g + 4);
        u16x8 o;
        o[0] = f2bf(f0.x); o[1] = f2bf(f0.y); o[2] = f2bf(f0.z); o[3] = f2bf(f0.w);
        o[4] = f2bf(f1.x); o[5] = f2bf(f1.y); o[6] = f2bf(f1.z); o[7] = f2bf(f1.w);
        *(u16x8*)(As + e) = o;
      }
    }
    __syncthreads();

    // ---- fragments: A lane l holds row (l&15), k = (l>>4)*8 + 0..7
    s16x8 af[4][2], bf[4][2];
#pragma unroll
    for (int m = 0; m < 4; ++m)
#pragma unroll
      for (int t = 0; t < 2; ++t)
        af[m][t] = *(const s16x8*)(As + (wr * 64 + m * 16 + l15) * BK + t * 32 + lk * 8);
#pragma unroll
    for (int n = 0; n < 4; ++n)
#pragma unroll
      for (int t = 0; t < 2; ++t)
        bf[n][t] = *(const s16x8*)(Bs + (wc * 64 + n * 16 + l15) * BK + t * 32 + lk * 8);

#pragma unroll
    for (int t = 0; t < 2; ++t)
#pragma unroll
      for (int m = 0; m < 4; ++m)
#pragma unroll
        for (int n = 0; n < 4; ++n)
          acc[m][n] = __builtin_amdgcn_mfma_f32_16x16x32_bf16(af[m][t], bf[n][t],
                                                              acc[m][n], 0, 0, 0);
    __syncthreads();
  }

  // ---- epilogue: C/D layout col = lane&15, row = (lane>>4)*4 + reg
  const int row0 = mTile + wr * 64, col0 = nTile + wc * 64;
#pragma unroll
  for (int n = 0; n < 4; ++n) {
    const int col = col0 + n * 16 + l15;
    const float bv = bias[col];
#pragma unroll
    for (int m = 0; m < 4; ++m) {
      const int r0 = row0 + m * 16 + lk * 4;
#pragma unroll
      for (int j = 0; j < 4; ++j)
        C[(size_t)(r0 + j) * NN + col] = acc[m][n][j] + bv;
    }
  }
}

extern "C" void kernel_launch(void* const* d_in, const int* in_sizes, int n_in,
                              void* d_out, int out_size, void* d_ws, size_t ws_size,
                              hipStream_t stream) {
  const float* x     = (const float*)d_in[0];  // (4,4096,1024)
  const float* w_qkv = (const float*)d_in[1];  // (3072,1024)
  const float* b_qkv = (const float*)d_in[2];  // (3072,)
  const float* a_q   = (const float*)d_in[3];  // (16,1024)
  const float* b_q   = (const float*)d_in[4];  // (1024,16)
  const float* a_v   = (const float*)d_in[5];
  const float* b_v   = (const float*)d_in[6];
  float* out = (float*)d_out;                  // (4,4096,3072) fp32

  u16* weff = (u16*)d_ws;
  const size_t weff_elems = (size_t)NN * KK;                 // 3,145,728
  u16* xb = weff + weff_elems;
  const size_t need = (weff_elems + (size_t)MM * KK) * sizeof(u16);  // ~40 MB

  build_weff<<<dim3(NN * KK / 256), dim3(256), 0, stream>>>(w_qkv, a_q, b_q,
                                                            a_v, b_v, weff);
  if (ws_size >= need) {
    cvt_x<<<dim3(MM * KK / 8 / 256), dim3(256), 0, stream>>>(x, xb);
    gemm_qkv<false><<<dim3(NN / BN, MM / BM), dim3(256), 0, stream>>>(
        xb, nullptr, weff, b_qkv, out);
  } else {
    gemm_qkv<true><<<dim3(NN / BN, MM / BM), dim3(256), 0, stream>>>(
        nullptr, x, weff, b_qkv, out);
  }
}

// Round 3
// 155.427 us; speedup vs baseline: 1.2042x; 1.2042x over previous
//
#include <hip/hip_runtime.h>

typedef unsigned int u32;
typedef unsigned short u16;
typedef short s16x8 __attribute__((ext_vector_type(8)));
typedef u16 u16x8 __attribute__((ext_vector_type(8)));
typedef float f32x4 __attribute__((ext_vector_type(4)));
typedef __attribute__((address_space(3))) u32 as3_u32;
typedef __attribute__((address_space(1))) const u32 as1_u32;

constexpr int MM = 16384, NN = 3072, KK = 1024;
constexpr int BM = 256, BN = 256, BK = 64;
constexpr int NT = KK / BK;  // 16 K-tiles

template <int V> struct IC { static constexpr int value = V; };

__device__ __forceinline__ u16 f2bf(float f) {
  u32 u = __builtin_bit_cast(u32, f);
  u = (u + 0x7FFFu + ((u >> 16) & 1u)) >> 16;
  return (u16)u;
}

__device__ __forceinline__ void gload_lds16(const void* g, void* l) {
  __builtin_amdgcn_global_load_lds((as1_u32*)g, (as3_u32*)l, 16, 0, 0);
}

// ---------- weight fold: W_eff = w + s*(b@a) on q/v slices, -> bf16 ----------
__global__ __launch_bounds__(256) void build_weff(
    const float* __restrict__ w, const float* __restrict__ aq,
    const float* __restrict__ bq, const float* __restrict__ av,
    const float* __restrict__ bv, u16* __restrict__ weff) {
  int idx = blockIdx.x * 256 + threadIdx.x;
  int o = idx >> 10, d = idx & 1023;
  float val = w[idx];
  if (o < 1024) {
    float s = 0.f;
#pragma unroll
    for (int r = 0; r < 16; ++r) s += bq[o * 16 + r] * aq[r * 1024 + d];
    val += s * 0.0625f;
  } else if (o >= 2048) {
    int o2 = o - 2048;
    float s = 0.f;
#pragma unroll
    for (int r = 0; r < 16; ++r) s += bv[o2 * 16 + r] * av[r * 1024 + d];
    val += s * 0.0625f;
  }
  weff[idx] = f2bf(val);
}

// ---------- x fp32 -> bf16 ----------
__global__ __launch_bounds__(256) void cvt_x(const float* __restrict__ x,
                                             u16* __restrict__ xb) {
  size_t i = ((size_t)blockIdx.x * 256 + threadIdx.x) * 8;
  float4 f0 = *(const float4*)(x + i);
  float4 f1 = *(const float4*)(x + i + 4);
  u16x8 o;
  o[0] = f2bf(f0.x); o[1] = f2bf(f0.y); o[2] = f2bf(f0.z); o[3] = f2bf(f0.w);
  o[4] = f2bf(f1.x); o[5] = f2bf(f1.y); o[6] = f2bf(f1.z); o[7] = f2bf(f1.w);
  *(u16x8*)(xb + i) = o;
}

// ---------- 256x256 8-phase GEMM: C = A @ B^T + bias ----------
// LDS swizzle: 16B slot index (bits 4-6 of row-local byte addr) XOR (row&7).
// Linear global_load_lds dest + inverse-swizzled global source + swizzled read.
// Stage schedule (race-free; all targets barrier-ordered past their readers):
//   P1: A0(t+1)->sA[cb^1]   P2: A1(t+1)->sA[cb^1]
//   P3: B0(t+2)->sB[cb]     P4: B1(t+2)->sB[cb]     gate vmcnt(4)
__global__ __launch_bounds__(512, 2) void gemm8p(
    const u16* __restrict__ Ag, const u16* __restrict__ Bg,
    const float* __restrict__ bias, float* __restrict__ C) {
  __shared__ __align__(16) u16 sA[2][BM * BK];  // 64 KB
  __shared__ __align__(16) u16 sB[2][BN * BK];  // 64 KB

  const int tid = threadIdx.x;
  const int wave = tid >> 6, lane = tid & 63;
  const int wrow = wave >> 2, wcol = wave & 3;        // 2 x 4 waves
  const int l15 = lane & 15, lk = lane >> 4;
  const int swz = (l15 & 7) << 4;                     // read-side byte xor
  const int ko0 = ((lk * 16) ^ swz) >> 1;             // ksub 0 (elements)
  const int ko1 = ((64 + lk * 16) ^ swz) >> 1;        // ksub 1
  const int sRow = lane >> 3;                         // staging src row 0..7
  const int sCol = ((lane & 7) ^ (lane >> 3)) << 3;   // inverse-swizzled col

  constexpr int NWG = (MM / BM) * (NN / BN);          // 768, %8==0
  const int b = blockIdx.x;
  const int bs = (b & 7) * (NWG >> 3) + (b >> 3);
  const int tileM = (bs / (NN / BN)) * BM;
  const int tileN = (bs % (NN / BN)) * BN;

  const u16* Agb = Ag + (size_t)tileM * KK;
  const u16* Bgb = Bg + (size_t)tileN * KK;

  f32x4 acc[8][4] = {};
  s16x8 a[4][2], bl[2][2], bh[2][2];

  auto STAGE = [&](const u16* __restrict__ G, int rowHalf, u16* ldsHalf, int kc) {
#pragma unroll
    for (int j = 0; j < 2; ++j) {
      const int c = wave * 2 + j;                     // chunk 0..15
      gload_lds16(G + (size_t)(rowHalf + c * 8 + sRow) * KK + kc + sCol,
                  ldsHalf + c * 512);
    }
  };
  auto LDA = [&](const u16* At, int mh) {
#pragma unroll
    for (int i = 0; i < 4; ++i) {
      const int row = wrow * 128 + (mh * 4 + i) * 16 + l15;
      const u16* p = At + row * 64;
      a[i][0] = *(const s16x8*)(p + ko0);
      a[i][1] = *(const s16x8*)(p + ko1);
    }
  };
  auto LDB = [&](s16x8 (&bf)[2][2], const u16* Bt, int nh) {
#pragma unroll
    for (int i = 0; i < 2; ++i) {
      const int row = wcol * 64 + (nh * 2 + i) * 16 + l15;
      const u16* p = Bt + row * 64;
      bf[i][0] = *(const s16x8*)(p + ko0);
      bf[i][1] = *(const s16x8*)(p + ko1);
    }
  };
  auto MFMA16 = [&](auto MH, auto NH, s16x8 (&bf)[2][2]) {
    constexpr int mh = decltype(MH)::value, nh = decltype(NH)::value;
    __builtin_amdgcn_s_setprio(1);
#pragma unroll
    for (int k2 = 0; k2 < 2; ++k2)
#pragma unroll
      for (int i = 0; i < 4; ++i)
#pragma unroll
        for (int j = 0; j < 2; ++j)
          acc[mh * 4 + i][nh * 2 + j] = __builtin_amdgcn_mfma_f32_16x16x32_bf16(
              a[i][k2], bf[j][k2], acc[mh * 4 + i][nh * 2 + j], 0, 0, 0);
    __builtin_amdgcn_s_setprio(0);
  };
  auto BAR = [] {
    asm volatile("" ::: "memory");
    __builtin_amdgcn_s_barrier();
    asm volatile("" ::: "memory");
  };

  // Tile t on buf cb. k1 = K-offset of tile t+1 (A stages), k2 = t+2 (B stages).
  auto KT = [&](int cb, int k1, int k2, int s1, int s2, int vm) {
    const u16* Ac = sA[cb]; const u16* Bc = sB[cb];
    // P1: quadrant (0,0)
    LDA(Ac, 0); LDB(bl, Bc, 0);
    if (s1) STAGE(Agb, 0, sA[cb ^ 1], k1);            // A0(t+1)
    BAR();
    MFMA16(IC<0>{}, IC<0>{}, bl);
    BAR();
    // P2: quadrant (0,1)
    LDB(bh, Bc, 1);
    if (s1) STAGE(Agb, 128, sA[cb ^ 1] + 8192, k1);   // A1(t+1)
    BAR();
    MFMA16(IC<0>{}, IC<1>{}, bh);
    BAR();
    // P3: quadrant (1,1)  — sB[cb] reads all done by end-P2 barrier
    LDA(Ac, 1);
    if (s2) STAGE(Bgb, 0, sB[cb], k2);                // B0(t+2)
    BAR();
    MFMA16(IC<1>{}, IC<1>{}, bh);
    BAR();
    // P4: quadrant (1,0)
    if (s2) STAGE(Bgb, 128, sB[cb] + 8192, k2);       // B1(t+2)
    BAR();
    MFMA16(IC<1>{}, IC<0>{}, bl);
    if (vm == 4) asm volatile("s_waitcnt vmcnt(4)" ::: "memory");
    else if (vm == 0) asm volatile("s_waitcnt vmcnt(0)" ::: "memory");
    BAR();
  };

  // Prologue: tile0 {A0,A1,B0,B1} + tile1 {B0,B1}; tile1 A staged in tile0.
  STAGE(Agb, 0,   sA[0], 0);
  STAGE(Agb, 128, sA[0] + 8192, 0);
  STAGE(Bgb, 0,   sB[0], 0);
  STAGE(Bgb, 128, sB[0] + 8192, 0);
  STAGE(Bgb, 0,   sB[1], BK);
  STAGE(Bgb, 128, sB[1] + 8192, BK);
  asm volatile("s_waitcnt vmcnt(4)" ::: "memory");    // tile0 landed
  BAR();

#pragma unroll 1
  for (int t = 0; t < NT - 2; t += 2) {               // tiles 0..13
    KT(0, (t + 1) * BK, (t + 2) * BK, 1, 1, 4);
    KT(1, (t + 2) * BK, (t + 3) * BK, 1, 1, 4);
  }
  KT(0, (NT - 1) * BK, 0, 1, 0, 0);                   // tile 14: drain all
  KT(1, 0, 0, 0, 0, -1);                              // tile 15

  // Epilogue: C/D layout col = lane&15, row = (lane>>4)*4 + reg
  const int r0 = tileM + wrow * 128, c0 = tileN + wcol * 64;
#pragma unroll
  for (int n = 0; n < 4; ++n) {
    const int col = c0 + n * 16 + l15;
    const float bv = bias[col];
#pragma unroll
    for (int m = 0; m < 8; ++m) {
      const int rr = r0 + m * 16 + lk * 4;
#pragma unroll
      for (int j = 0; j < 4; ++j)
        C[(size_t)(rr + j) * NN + col] = acc[m][n][j] + bv;
    }
  }
}

// ---------- fallback (ws too small): 128^2 reg-staged fp32 A ----------
__global__ __launch_bounds__(256) void gemm_fb(
    const float* __restrict__ Af, const u16* __restrict__ Bw,
    const float* __restrict__ bias, float* __restrict__ C) {
  __shared__ u16 As[128 * 64];
  __shared__ u16 Bs[128 * 64];
  const int tid = threadIdx.x;
  const int wave = tid >> 6, lane = tid & 63;
  const int l15 = lane & 15, lkq = lane >> 4;
  const int mTile = blockIdx.y * 128, nTile = blockIdx.x * 128;
  const int wr = wave >> 1, wc = wave & 1;
  f32x4 acc[4][4] = {};
  for (int k0 = 0; k0 < KK; k0 += 64) {
#pragma unroll
    for (int j = 0; j < 4; ++j) {
      const int c = wave * 4 + j;
      const int e = c * 512 + lane * 8;
      const int row = e >> 6, col = e & 63;
      gload_lds16(Bw + (size_t)(nTile + row) * KK + k0 + col, Bs + c * 512);
    }
#pragma unroll
    for (int j = 0; j < 4; ++j) {
      const int e = (j * 256 + tid) * 8;
      const int row = e >> 6, col = e & 63;
      const float* g = Af + (size_t)(mTile + row) * KK + k0 + col;
      float4 f0 = *(const float4*)g;
      float4 f1 = *(const float4*)(g + 4);
      u16x8 o;
      o[0] = f2bf(f0.x); o[1] = f2bf(f0.y); o[2] = f2bf(f0.z); o[3] = f2bf(f0.w);
      o[4] = f2bf(f1.x); o[5] = f2bf(f1.y); o[6] = f2bf(f1.z); o[7] = f2bf(f1.w);
      *(u16x8*)(As + e) = o;
    }
    __syncthreads();
    s16x8 af[4][2], bf[4][2];
#pragma unroll
    for (int m = 0; m < 4; ++m)
#pragma unroll
      for (int t = 0; t < 2; ++t)
        af[m][t] = *(const s16x8*)(As + (wr * 64 + m * 16 + l15) * 64 + t * 32 + lkq * 8);
#pragma unroll
    for (int n = 0; n < 4; ++n)
#pragma unroll
      for (int t = 0; t < 2; ++t)
        bf[n][t] = *(const s16x8*)(Bs + (wc * 64 + n * 16 + l15) * 64 + t * 32 + lkq * 8);
#pragma unroll
    for (int t = 0; t < 2; ++t)
#pragma unroll
      for (int m = 0; m < 4; ++m)
#pragma unroll
        for (int n = 0; n < 4; ++n)
          acc[m][n] = __builtin_amdgcn_mfma_f32_16x16x32_bf16(af[m][t], bf[n][t],
                                                              acc[m][n], 0, 0, 0);
    __syncthreads();
  }
  const int row0 = mTile + wr * 64, col0 = nTile + wc * 64;
#pragma unroll
  for (int n = 0; n < 4; ++n) {
    const int col = col0 + n * 16 + l15;
    const float bv = bias[col];
#pragma unroll
    for (int m = 0; m < 4; ++m) {
      const int rr = row0 + m * 16 + lkq * 4;
#pragma unroll
      for (int j = 0; j < 4; ++j)
        C[(size_t)(rr + j) * NN + col] = acc[m][n][j] + bv;
    }
  }
}

extern "C" void kernel_launch(void* const* d_in, const int* in_sizes, int n_in,
                              void* d_out, int out_size, void* d_ws, size_t ws_size,
                              hipStream_t stream) {
  const float* x     = (const float*)d_in[0];
  const float* w_qkv = (const float*)d_in[1];
  const float* b_qkv = (const float*)d_in[2];
  const float* a_q   = (const float*)d_in[3];
  const float* b_q   = (const float*)d_in[4];
  const float* a_v   = (const float*)d_in[5];
  const float* b_v   = (const float*)d_in[6];
  float* out = (float*)d_out;

  u16* weff = (u16*)d_ws;
  const size_t weff_elems = (size_t)NN * KK;
  u16* xb = weff + weff_elems;
  const size_t need = (weff_elems + (size_t)MM * KK) * sizeof(u16);

  build_weff<<<dim3(NN * KK / 256), dim3(256), 0, stream>>>(w_qkv, a_q, b_q,
                                                            a_v, b_v, weff);
  if (ws_size >= need) {
    cvt_x<<<dim3(MM * KK / 8 / 256), dim3(256), 0, stream>>>(x, xb);
    gemm8p<<<dim3((MM / BM) * (NN / BN)), dim3(512), 0, stream>>>(xb, weff,
                                                                  b_qkv, out);
  } else {
    gemm_fb<<<dim3(NN / 128, MM / 128), dim3(256), 0, stream>>>(x, weff,
                                                                b_qkv, out);
  }
}

// Round 4
// 149.757 us; speedup vs baseline: 1.2497x; 1.0379x over previous
//
#include <hip/hip_runtime.h>

typedef unsigned int u32;
typedef unsigned short u16;
typedef short s16x8 __attribute__((ext_vector_type(8)));
typedef u16 u16x8 __attribute__((ext_vector_type(8)));
typedef float f32x4 __attribute__((ext_vector_type(4)));
typedef __attribute__((address_space(3))) u32 as3_u32;
typedef __attribute__((address_space(1))) const u32 as1_u32;

constexpr int MM = 16384, NN = 3072, KK = 1024;
constexpr int BM = 256, BN = 256, BK = 64;
constexpr int NT = KK / BK;  // 16 K-tiles

template <int V> struct IC { static constexpr int value = V; };

__device__ __forceinline__ u16 f2bf(float f) {
  u32 u = __builtin_bit_cast(u32, f);
  u = (u + 0x7FFFu + ((u >> 16) & 1u)) >> 16;
  return (u16)u;
}

__device__ __forceinline__ void gload_lds16(const void* g, void* l) {
  __builtin_amdgcn_global_load_lds((as1_u32*)g, (as3_u32*)l, 16, 0, 0);
}

// ---------- merged prep: blocks [0,12288) fold weights, [12288,20480) cvt x ----------
constexpr int WEFF_BLOCKS = NN * KK / 256;            // 12288
constexpr int CVT_BLOCKS = MM * KK / 8 / 256;         // 8192
__global__ __launch_bounds__(256) void prep(
    const float* __restrict__ w, const float* __restrict__ aq,
    const float* __restrict__ bq, const float* __restrict__ av,
    const float* __restrict__ bv, u16* __restrict__ weff,
    const float* __restrict__ x, u16* __restrict__ xb) {
  const int bid = blockIdx.x;
  if (bid < WEFF_BLOCKS) {
    int idx = bid * 256 + threadIdx.x;
    int o = idx >> 10, d = idx & 1023;
    float val = w[idx];
    if (o < 1024) {
      float s = 0.f;
#pragma unroll
      for (int r = 0; r < 16; ++r) s += bq[o * 16 + r] * aq[r * 1024 + d];
      val += s * 0.0625f;                              // SCALING = 1/16
    } else if (o >= 2048) {
      int o2 = o - 2048;
      float s = 0.f;
#pragma unroll
      for (int r = 0; r < 16; ++r) s += bv[o2 * 16 + r] * av[r * 1024 + d];
      val += s * 0.0625f;
    }
    weff[idx] = f2bf(val);
  } else {
    size_t i = ((size_t)(bid - WEFF_BLOCKS) * 256 + threadIdx.x) * 8;
    float4 f0 = *(const float4*)(x + i);
    float4 f1 = *(const float4*)(x + i + 4);
    u16x8 o;
    o[0] = f2bf(f0.x); o[1] = f2bf(f0.y); o[2] = f2bf(f0.z); o[3] = f2bf(f0.w);
    o[4] = f2bf(f1.x); o[5] = f2bf(f1.y); o[6] = f2bf(f1.z); o[7] = f2bf(f1.w);
    *(u16x8*)(xb + i) = o;
  }
}

// ---------- 256x256 GEMM, 4-barrier relaxed-lockstep schedule ----------
// LDS swizzle: 16B slot index XOR (row&7); linear gload_lds dest +
// inverse-swizzled global source + swizzled read. Verified conflict-free (R3).
// Per tile t (buf cb):
//   R1: [LDA a0; LDB bl; STAGE A0(t+1)->sA[cb^1]h0]                BAR1
//   R2: [MFMA(0,0); LDB bh; STAGE A1(t+1)->sA[cb^1]h1; lgkm(0)]    BAR2
//   R3: [MFMA(0,1); LDA a1; STAGE B0(t+2)->sB[cb]h0]               BAR3
//   R4: [MFMA(1,1); STAGE B1(t+2)->sB[cb]h1; MFMA(1,0); vmcnt(4)]  BAR4
// Safety: stage->region readers are lgkm-complete before the barrier each
// stage follows (A: one tile earlier; B0: forced by lgkm(0)@BAR2; B1: bl/bh
// consumed in R2/R3 MFMAs). vmcnt(4) leaves exactly B0,B1(t+2) in flight.
__global__ __launch_bounds__(512, 2) void gemm8p(
    const u16* __restrict__ Ag, const u16* __restrict__ Bg,
    const float* __restrict__ bias, float* __restrict__ C) {
  __shared__ __align__(16) u16 sA[2][BM * BK];  // 64 KB
  __shared__ __align__(16) u16 sB[2][BN * BK];  // 64 KB

  const int tid = threadIdx.x;
  const int wave = tid >> 6, lane = tid & 63;
  const int wrow = wave >> 2, wcol = wave & 3;        // 2 x 4 waves
  const int l15 = lane & 15, lk = lane >> 4;
  const int swz = (l15 & 7) << 4;                     // read-side byte xor
  const int ko0 = ((lk * 16) ^ swz) >> 1;             // ksub 0 (elements)
  const int ko1 = ((64 + lk * 16) ^ swz) >> 1;        // ksub 1
  const int sRow = lane >> 3;                         // staging src row 0..7
  const int sCol = ((lane & 7) ^ (lane >> 3)) << 3;   // inverse-swizzled col

  constexpr int NWG = (MM / BM) * (NN / BN);          // 768, %8==0
  const int b = blockIdx.x;
  const int bs = (b & 7) * (NWG >> 3) + (b >> 3);
  const int tileM = (bs / (NN / BN)) * BM;
  const int tileN = (bs % (NN / BN)) * BN;

  const u16* Agb = Ag + (size_t)tileM * KK;
  const u16* Bgb = Bg + (size_t)tileN * KK;

  f32x4 acc[8][4] = {};
  s16x8 a[4][2], bl[2][2], bh[2][2];

  auto STAGE = [&](const u16* __restrict__ G, int rowHalf, u16* ldsHalf, int kc) {
#pragma unroll
    for (int j = 0; j < 2; ++j) {
      const int c = wave * 2 + j;                     // chunk 0..15
      gload_lds16(G + (size_t)(rowHalf + c * 8 + sRow) * KK + kc + sCol,
                  ldsHalf + c * 512);
    }
  };
  auto LDA = [&](const u16* At, int mh) {
#pragma unroll
    for (int i = 0; i < 4; ++i) {
      const int row = wrow * 128 + (mh * 4 + i) * 16 + l15;
      const u16* p = At + row * 64;
      a[i][0] = *(const s16x8*)(p + ko0);
      a[i][1] = *(const s16x8*)(p + ko1);
    }
  };
  auto LDB = [&](s16x8 (&bf)[2][2], const u16* Bt, int nh) {
#pragma unroll
    for (int i = 0; i < 2; ++i) {
      const int row = wcol * 64 + (nh * 2 + i) * 16 + l15;
      const u16* p = Bt + row * 64;
      bf[i][0] = *(const s16x8*)(p + ko0);
      bf[i][1] = *(const s16x8*)(p + ko1);
    }
  };
  auto MFMA16 = [&](auto MH, auto NH, s16x8 (&bf)[2][2]) {
    constexpr int mh = decltype(MH)::value, nh = decltype(NH)::value;
    __builtin_amdgcn_s_setprio(1);
#pragma unroll
    for (int k2 = 0; k2 < 2; ++k2)
#pragma unroll
      for (int i = 0; i < 4; ++i)
#pragma unroll
        for (int j = 0; j < 2; ++j)
          acc[mh * 4 + i][nh * 2 + j] = __builtin_amdgcn_mfma_f32_16x16x32_bf16(
              a[i][k2], bf[j][k2], acc[mh * 4 + i][nh * 2 + j], 0, 0, 0);
    __builtin_amdgcn_s_setprio(0);
  };
  auto BAR = [] {
    asm volatile("" ::: "memory");
    __builtin_amdgcn_s_barrier();
    asm volatile("" ::: "memory");
  };

  auto KT = [&](int cb, int k1, int k2, int s1, int s2, int vm) {
    const u16* Ac = sA[cb]; const u16* Bc = sB[cb];
    // R1
    LDA(Ac, 0); LDB(bl, Bc, 0);
    if (s1) STAGE(Agb, 0, sA[cb ^ 1], k1);            // A0(t+1)
    BAR();
    // R2
    MFMA16(IC<0>{}, IC<0>{}, bl);
    LDB(bh, Bc, 1);
    if (s1) STAGE(Agb, 128, sA[cb ^ 1] + 8192, k1);   // A1(t+1)
    asm volatile("s_waitcnt lgkmcnt(0)" ::: "memory"); // all sB readers drained
    BAR();
    // R3
    MFMA16(IC<0>{}, IC<1>{}, bh);
    LDA(Ac, 1);
    if (s2) STAGE(Bgb, 0, sB[cb], k2);                // B0(t+2)
    BAR();
    // R4
    MFMA16(IC<1>{}, IC<1>{}, bh);
    if (s2) STAGE(Bgb, 128, sB[cb] + 8192, k2);       // B1(t+2)
    MFMA16(IC<1>{}, IC<0>{}, bl);
    if (vm == 4) asm volatile("s_waitcnt vmcnt(4)" ::: "memory");
    else if (vm == 0) asm volatile("s_waitcnt vmcnt(0)" ::: "memory");
    BAR();
  };

  // Prologue: tile0 {A0,A1,B0,B1} + tile1 {B0,B1}
  STAGE(Agb, 0,   sA[0], 0);
  STAGE(Agb, 128, sA[0] + 8192, 0);
  STAGE(Bgb, 0,   sB[0], 0);
  STAGE(Bgb, 128, sB[0] + 8192, 0);
  STAGE(Bgb, 0,   sB[1], BK);
  STAGE(Bgb, 128, sB[1] + 8192, BK);
  asm volatile("s_waitcnt vmcnt(4)" ::: "memory");    // tile0 landed
  BAR();

#pragma unroll 1
  for (int t = 0; t < NT - 2; t += 2) {               // tiles 0..13
    KT(0, (t + 1) * BK, (t + 2) * BK, 1, 1, 4);
    KT(1, (t + 2) * BK, (t + 3) * BK, 1, 1, 4);
  }
  KT(0, (NT - 1) * BK, 0, 1, 0, 0);                   // tile 14: drain all
  KT(1, 0, 0, 0, 0, -1);                              // tile 15

  // Epilogue: C/D layout col = lane&15, row = (lane>>4)*4 + reg
  const int r0 = tileM + wrow * 128, c0 = tileN + wcol * 64;
#pragma unroll
  for (int n = 0; n < 4; ++n) {
    const int col = c0 + n * 16 + l15;
    const float bv = bias[col];
#pragma unroll
    for (int m = 0; m < 8; ++m) {
      const int rr = r0 + m * 16 + lk * 4;
#pragma unroll
      for (int j = 0; j < 4; ++j)
        C[(size_t)(rr + j) * NN + col] = acc[m][n][j] + bv;
    }
  }
}

// ---------- fallback (ws too small): 128^2 reg-staged fp32 A ----------
__global__ __launch_bounds__(256) void gemm_fb(
    const float* __restrict__ Af, const u16* __restrict__ Bw,
    const float* __restrict__ bias, float* __restrict__ C) {
  __shared__ u16 As[128 * 64];
  __shared__ u16 Bs[128 * 64];
  const int tid = threadIdx.x;
  const int wave = tid >> 6, lane = tid & 63;
  const int l15 = lane & 15, lkq = lane >> 4;
  const int mTile = blockIdx.y * 128, nTile = blockIdx.x * 128;
  const int wr = wave >> 1, wc = wave & 1;
  f32x4 acc[4][4] = {};
  for (int k0 = 0; k0 < KK; k0 += 64) {
#pragma unroll
    for (int j = 0; j < 4; ++j) {
      const int c = wave * 4 + j;
      const int e = c * 512 + lane * 8;
      const int row = e >> 6, col = e & 63;
      gload_lds16(Bw + (size_t)(nTile + row) * KK + k0 + col, Bs + c * 512);
    }
#pragma unroll
    for (int j = 0; j < 4; ++j) {
      const int e = (j * 256 + tid) * 8;
      const int row = e >> 6, col = e & 63;
      const float* g = Af + (size_t)(mTile + row) * KK + k0 + col;
      float4 f0 = *(const float4*)g;
      float4 f1 = *(const float4*)(g + 4);
      u16x8 o;
      o[0] = f2bf(f0.x); o[1] = f2bf(f0.y); o[2] = f2bf(f0.z); o[3] = f2bf(f0.w);
      o[4] = f2bf(f1.x); o[5] = f2bf(f1.y); o[6] = f2bf(f1.z); o[7] = f2bf(f1.w);
      *(u16x8*)(As + e) = o;
    }
    __syncthreads();
    s16x8 af[4][2], bf[4][2];
#pragma unroll
    for (int m = 0; m < 4; ++m)
#pragma unroll
      for (int t = 0; t < 2; ++t)
        af[m][t] = *(const s16x8*)(As + (wr * 64 + m * 16 + l15) * 64 + t * 32 + lkq * 8);
#pragma unroll
    for (int n = 0; n < 4; ++n)
#pragma unroll
      for (int t = 0; t < 2; ++t)
        bf[n][t] = *(const s16x8*)(Bs + (wc * 64 + n * 16 + l15) * 64 + t * 32 + lkq * 8);
#pragma unroll
    for (int t = 0; t < 2; ++t)
#pragma unroll
      for (int m = 0; m < 4; ++m)
#pragma unroll
        for (int n = 0; n < 4; ++n)
          acc[m][n] = __builtin_amdgcn_mfma_f32_16x16x32_bf16(af[m][t], bf[n][t],
                                                              acc[m][n], 0, 0, 0);
    __syncthreads();
  }
  const int row0 = mTile + wr * 64, col0 = nTile + wc * 64;
#pragma unroll
  for (int n = 0; n < 4; ++n) {
    const int col = col0 + n * 16 + l15;
    const float bv = bias[col];
#pragma unroll
    for (int m = 0; m < 4; ++m) {
      const int rr = row0 + m * 16 + lkq * 4;
#pragma unroll
      for (int j = 0; j < 4; ++j)
        C[(size_t)(rr + j) * NN + col] = acc[m][n][j] + bv;
    }
  }
}

extern "C" void kernel_launch(void* const* d_in, const int* in_sizes, int n_in,
                              void* d_out, int out_size, void* d_ws, size_t ws_size,
                              hipStream_t stream) {
  const float* x     = (const float*)d_in[0];
  const float* w_qkv = (const float*)d_in[1];
  const float* b_qkv = (const float*)d_in[2];
  const float* a_q   = (const float*)d_in[3];
  const float* b_q   = (const float*)d_in[4];
  const float* a_v   = (const float*)d_in[5];
  const float* b_v   = (const float*)d_in[6];
  float* out = (float*)d_out;

  u16* weff = (u16*)d_ws;
  const size_t weff_elems = (size_t)NN * KK;
  u16* xb = weff + weff_elems;
  const size_t need = (weff_elems + (size_t)MM * KK) * sizeof(u16);

  if (ws_size >= need) {
    prep<<<dim3(WEFF_BLOCKS + CVT_BLOCKS), dim3(256), 0, stream>>>(
        w_qkv, a_q, b_q, a_v, b_v, weff, x, xb);
    gemm8p<<<dim3((MM / BM) * (NN / BN)), dim3(512), 0, stream>>>(xb, weff,
                                                                  b_qkv, out);
  } else {
    prep<<<dim3(WEFF_BLOCKS), dim3(256), 0, stream>>>(w_qkv, a_q, b_q, a_v,
                                                      b_v, weff, x, nullptr);
    gemm_fb<<<dim3(NN / 128, MM / 128), dim3(256), 0, stream>>>(x, weff,
                                                                b_qkv, out);
  }
}